// Round 4
// baseline (688.111 us; speedup 1.0000x reference)
//
#include <hip/hip_runtime.h>

// Self-attention B=2, S=4096, D=1024, fp32 in/out.
//
// Round-4: fix round-3's Mt transpose flip.
//   scores = E*(Wq*Wk^T)*E^T.  NT-GEMM B-operand must be
//   Mt[d'][d] = sum_e Wq[d][e]*Wk[d'][e]  ==  NT-GEMM(A=Wk, B=Wq) on the
//   ORIGINAL row-major weights (reduction over contiguous e) -- round 3
//   wrongly fed the transposed weights (computed Wk^T*Wq).
//
//  * QM trick: scores = (E*M)*E^T, M = Wq*Wk^T precomputed once.
//  * Tripled-K split-bf16 emulation: fp32-accurate GEMMs as ONE plain bf16
//    NT GEMM over segmented K, A-pattern (h,h,l) x B-pattern (h,l,h).
//  * Engine: m97-style 128x128x32, global_load_lds width-16 (round-2-proven).
//
// Per batch: split_emb -> QMproj -> scores(+mask,scale,fp32) -> Vtproj
// -> in-place softmax (bf16 P over fp32 scores rows) -> PV -> out.

#define S_LEN 4096

typedef __bf16 bf16x8 __attribute__((ext_vector_type(8)));
typedef float f32x4 __attribute__((ext_vector_type(4)));

struct Segs { const unsigned short* p[4]; };

__device__ __forceinline__ unsigned short f2bf(float x) {
  unsigned u = __float_as_uint(x);
  unsigned r = u + 0x7fffu + ((u >> 16) & 1u);  // round-to-nearest-even
  return (unsigned short)(r >> 16);
}
__device__ __forceinline__ float bf2f(unsigned short h) {
  return __uint_as_float(((unsigned)h) << 16);
}

__device__ __forceinline__ void gl_lds16(const void* g, void* l) {
  __builtin_amdgcn_global_load_lds(
      (const __attribute__((address_space(1))) void*)g,
      (__attribute__((address_space(3))) void*)l, 16, 0, 0);
}

// ---------------------------------------------------------------------------
// split32: fp32 -> (hi, lo) bf16 pair, elementwise, float4-vectorized.
// grid * 256 * 4 must equal the element count.
__launch_bounds__(256)
__global__ void split32(const float* __restrict__ e,
                        unsigned short* __restrict__ Eh,
                        unsigned short* __restrict__ El) {
  int i = blockIdx.x * 256 + threadIdx.x;  // float4 index
  float4 v = reinterpret_cast<const float4*>(e)[i];
  ushort4 h, l;
  h.x = f2bf(v.x); l.x = f2bf(v.x - bf2f(h.x));
  h.y = f2bf(v.y); l.y = f2bf(v.y - bf2f(h.y));
  h.z = f2bf(v.z); l.z = f2bf(v.z - bf2f(h.z));
  h.w = f2bf(v.w); l.w = f2bf(v.w - bf2f(h.w));
  reinterpret_cast<ushort4*>(Eh)[i] = h;
  reinterpret_cast<ushort4*>(El)[i] = l;
}

// ---------------------------------------------------------------------------
// prep_wv: Wv[d][e] -> Wvt[e][d] plain bf16. 32x32 LDS transpose.
__launch_bounds__(256)
__global__ void prep_wv(const float* __restrict__ wv, unsigned short* __restrict__ Wvt) {
  __shared__ float tile[32][33];
  const int bx = blockIdx.x * 32;  // e block
  const int by = blockIdx.y * 32;  // d block
  const int tx = threadIdx.x;      // 0..31
  const int ty = threadIdx.y;      // 0..7
#pragma unroll
  for (int j = 0; j < 4; ++j)
    tile[ty + j * 8][tx] = wv[(long)(by + ty + j * 8) * 1024 + bx + tx];
  __syncthreads();
#pragma unroll
  for (int j = 0; j < 4; ++j) {
    float v = tile[tx][ty + j * 8];  // = Wv[by+tx][bx+ty+j*8]
    Wvt[(long)(bx + ty + j * 8) * 1024 + by + tx] = f2bf(v);
  }
}

// ---------------------------------------------------------------------------
// Segmented NT GEMM: C[m][n] = sum_s sum_{k<1024} A.p[s][m*lda+k]*B.p[s][n*ldb+k].
// BM=BN=128, BK=32, 4 waves, 4x4 16x16x32 bf16 fragments per wave.
// MODE 0: hi/lo bf16 pair store (Cp=hi, C2=lo)    [M precompute, QM proj]
// MODE 1: fp32 store of acc*scale + mask_filled^T  [scores]
// MODE 2: plain bf16 store                         [Vt projection]
// MODE 3: fp32 store                               [output PV]
template <int MODE>
__launch_bounds__(256)
__global__ void gemm3(Segs A, int lda, Segs B, int ldb,
                      void* __restrict__ Cp, int ldc,
                      unsigned short* __restrict__ C2,
                      const float* __restrict__ mask, float scale, int nseg) {
  __shared__ unsigned short lA[128 * 32];
  __shared__ unsigned short lB[128 * 32];

  const int t = threadIdx.x;
  const int w = t >> 6;
  const int lane = t & 63;
  const int g = lane >> 4;
  const int r = lane & 15;
  const int wm = (w >> 1) * 64;
  const int wn = (w & 1) * 64;
  const long bm = (long)blockIdx.x * 128;
  const long bn = (long)blockIdx.y * 128;

  f32x4 acc[4][4];
  const f32x4 vzero = {0.f, 0.f, 0.f, 0.f};
#pragma unroll
  for (int mi = 0; mi < 4; ++mi)
#pragma unroll
    for (int ni = 0; ni < 4; ++ni) acc[mi][ni] = vzero;

  for (int s = 0; s < nseg; ++s) {
    const unsigned short* As = A.p[s];
    const unsigned short* Bs = B.p[s];
    for (int kt = 0; kt < 32; ++kt) {
      __syncthreads();
      const int kbase = kt * 32;
#pragma unroll
      for (int i = 0; i < 2; ++i) {
        // chunk c in [0,512): 16B granules of the 128x32 bf16 tile (row-major)
        int c = (i * 4 + w) * 64 + lane;
        int row = c >> 2;
        int ko = (c & 3) * 8;
        int lbase = (i * 4 + w) * 512;  // wave-uniform LDS base (ushort units)
        gl_lds16(As + (bm + row) * (long)lda + kbase + ko, lA + lbase);
        gl_lds16(Bs + (bn + row) * (long)ldb + kbase + ko, lB + lbase);
      }
      __syncthreads();

      bf16x8 af[4], bfr[4];
#pragma unroll
      for (int mi = 0; mi < 4; ++mi)
        af[mi] = *reinterpret_cast<const bf16x8*>(&lA[(wm + mi * 16 + r) * 32 + g * 8]);
#pragma unroll
      for (int ni = 0; ni < 4; ++ni)
        bfr[ni] = *reinterpret_cast<const bf16x8*>(&lB[(wn + ni * 16 + r) * 32 + g * 8]);
#pragma unroll
      for (int mi = 0; mi < 4; ++mi)
#pragma unroll
        for (int ni = 0; ni < 4; ++ni)
          acc[mi][ni] = __builtin_amdgcn_mfma_f32_16x16x32_bf16(af[mi], bfr[ni], acc[mi][ni], 0, 0, 0);
    }
  }

  // Epilogue. C/D layout: col = lane&15, row = 4*(lane>>4) + reg (m89-verified).
#pragma unroll
  for (int mi = 0; mi < 4; ++mi) {
#pragma unroll
    for (int ni = 0; ni < 4; ++ni) {
      long row0 = bm + wm + mi * 16 + g * 4;
      long col = bn + wn + ni * 16 + r;
#pragma unroll
      for (int q = 0; q < 4; ++q) {
        float v = acc[mi][ni][q];
        long row = row0 + q;
        if constexpr (MODE == 0) {
          unsigned short h = f2bf(v);
          ((unsigned short*)Cp)[row * (long)ldc + col] = h;
          C2[row * (long)ldc + col] = f2bf(v - bf2f(h));
        } else if constexpr (MODE == 1) {
          // scores[q_row][k_col]: add mask_filled.T = mask[k][q] (or -inf)
          float mv = mask[col * (long)S_LEN + row];
          v = v * scale;
          v = (mv == 0.0f) ? -__builtin_inff() : (v + mv);
          ((float*)Cp)[row * (long)ldc + col] = v;
        } else if constexpr (MODE == 2) {
          ((unsigned short*)Cp)[row * (long)ldc + col] = f2bf(v);
        } else {
          ((float*)Cp)[row * (long)ldc + col] = v;
        }
      }
    }
  }
}

// ---------------------------------------------------------------------------
// Row softmax, IN PLACE: reads 4096 fp32 of row blockIdx.x, writes 4096 bf16
// into the first half of the same row's storage (row stride stays 8192 ushorts).
__launch_bounds__(256)
__global__ void softmax_rows(float* __restrict__ Sc) {
  const long row = blockIdx.x;
  float* sr = Sc + row * (long)S_LEN;
  unsigned short* pr = (unsigned short*)sr;
  const int t = threadIdx.x;
  const int lane = t & 63, wid = t >> 6;

  float4 x[4];
  float m = -3.0e38f;
#pragma unroll
  for (int i = 0; i < 4; ++i) {
    x[i] = reinterpret_cast<const float4*>(sr)[t + i * 256];
    m = fmaxf(m, fmaxf(fmaxf(x[i].x, x[i].y), fmaxf(x[i].z, x[i].w)));
  }
#pragma unroll
  for (int o = 32; o; o >>= 1) m = fmaxf(m, __shfl_xor(m, o));
  __shared__ float redm[4];
  __shared__ float reds[4];
  if (lane == 0) redm[wid] = m;
  __syncthreads();
  m = fmaxf(fmaxf(redm[0], redm[1]), fmaxf(redm[2], redm[3]));

  float e[16];
  float s = 0.f;
#pragma unroll
  for (int i = 0; i < 4; ++i) {
    e[i * 4 + 0] = __expf(x[i].x - m);
    e[i * 4 + 1] = __expf(x[i].y - m);
    e[i * 4 + 2] = __expf(x[i].z - m);
    e[i * 4 + 3] = __expf(x[i].w - m);
    s += e[i * 4 + 0] + e[i * 4 + 1] + e[i * 4 + 2] + e[i * 4 + 3];
  }
#pragma unroll
  for (int o = 32; o; o >>= 1) s += __shfl_xor(s, o);
  if (lane == 0) reds[wid] = s;
  __syncthreads();
  s = reds[0] + reds[1] + reds[2] + reds[3];
  float inv = 1.0f / s;
#pragma unroll
  for (int i = 0; i < 4; ++i) {
    ushort4 o4;
    o4.x = f2bf(e[i * 4 + 0] * inv);
    o4.y = f2bf(e[i * 4 + 1] * inv);
    o4.z = f2bf(e[i * 4 + 2] * inv);
    o4.w = f2bf(e[i * 4 + 3] * inv);
    reinterpret_cast<ushort4*>(pr)[t + i * 256] = o4;
  }
}

// ---------------------------------------------------------------------------
extern "C" void kernel_launch(void* const* d_in, const int* in_sizes, int n_in,
                              void* d_out, int out_size, void* d_ws, size_t ws_size,
                              hipStream_t stream) {
  const float* emb  = (const float*)d_in[0];
  const float* mask = (const float*)d_in[1];
  const float* wq   = (const float*)d_in[2];
  const float* wk   = (const float*)d_in[3];
  const float* wv   = (const float*)d_in[4];
  float* out = (float*)d_out;
  char* ws = (char*)d_ws;

  // Workspace layout (bytes):
  //  0        Eh   [4096][1024] bf16   8,388,608
  //  8388608  El   [4096][1024] bf16   8,388,608
  //  16777216 QMh  [4096][1024] bf16   8,388,608  (after scores: Vt [1024][4096] aliases)
  //  25165824 QMl  [4096][1024] bf16   8,388,608
  //  33554432 MtH  [1024][1024] bf16   2,097,152  (Mt[d'][d] = sum_e Wq[d][e] Wk[d'][e])
  //  35651584 MtL  [1024][1024] bf16   2,097,152
  //  37748736 Wvt  [1024][1024] bf16   2,097,152
  //  39845888 scores [4096][4096] f32 67,108,864
  //    (start of scores region aliases: WqH 2M | WqL 2M | WkH 2M | WkL 2M,
  //     dead before the first scores write)
  //  need = 106,954,752  (round-2-proven envelope: 109,051,904)
  const size_t need = 106954752;
  if (ws_size < need) return;  // clean absmax fail instead of a fault (diagnostic)

  unsigned short* Eh  = (unsigned short*)(ws);
  unsigned short* El  = (unsigned short*)(ws + 8388608);
  unsigned short* QMh = (unsigned short*)(ws + 16777216);
  unsigned short* QMl = (unsigned short*)(ws + 25165824);
  unsigned short* Vt  = QMh;  // alias, live only after scores
  unsigned short* MtH = (unsigned short*)(ws + 33554432);
  unsigned short* MtL = (unsigned short*)(ws + 35651584);
  unsigned short* Wvt = (unsigned short*)(ws + 37748736);
  float* scores       = (float*)(ws + 39845888);
  unsigned short* WqH = (unsigned short*)(ws + 39845888);
  unsigned short* WqL = (unsigned short*)(ws + 39845888 + 2097152);
  unsigned short* WkH = (unsigned short*)(ws + 39845888 + 4194304);
  unsigned short* WkL = (unsigned short*)(ws + 39845888 + 6291456);

  // ---- once: split weights (ORIGINAL layout), transpose Wv, precompute Mt --
  split32<<<1024, 256, 0, stream>>>(wq, WqH, WqL);
  split32<<<1024, 256, 0, stream>>>(wk, WkH, WkL);
  prep_wv<<<dim3(32, 32), dim3(32, 8), 0, stream>>>(wv, Wvt);
  {
    // Mt[d'][d] = sum_e Wk[d'][e]*Wq[d][e]: A=Wk (h,h,l), B=Wq (h,l,h).
    Segs a = {{WkH, WkH, WkL, nullptr}};
    Segs b = {{WqH, WqL, WqH, nullptr}};
    gemm3<0><<<dim3(8, 8), 256, 0, stream>>>(a, 1024, b, 1024, (void*)MtH, 1024, MtL,
                                             nullptr, 0.f, 3);
  }

  for (int b = 0; b < 2; ++b) {
    const float* embb = emb + (size_t)b * 4096 * 1024;
    float* outb = out + (size_t)b * 4096 * 1024;

    // 1) split embeddings into bf16 hi/lo
    split32<<<4096, 256, 0, stream>>>(embb, Eh, El);
    // 2) QM[s][d'] = sum_d E[s][d]*Mt[d'][d]: A=E (h,h,l), B=Mt (h,l,h)
    {
      Segs a = {{Eh, Eh, El, nullptr}};
      Segs bb = {{MtH, MtL, MtH, nullptr}};
      gemm3<0><<<dim3(32, 8), 256, 0, stream>>>(a, 1024, bb, 1024, (void*)QMh, 1024, QMl,
                                                nullptr, 0.f, 3);
    }
    // 3) scores = (QM * E^T)/32 + mask_filled^T: A=QM (h,l,h), B=E (h,h,l)
    {
      Segs a = {{QMh, QMl, QMh, nullptr}};
      Segs bb = {{Eh, Eh, El, nullptr}};
      gemm3<1><<<dim3(32, 32), 256, 0, stream>>>(a, 1024, bb, 1024, (void*)scores, 4096,
                                                 nullptr, mask, 0.03125f, 3);
    }
    // 4) Vt[e][s] = sum_d Wvt[e][d]*E[s][d] (plain bf16; overwrites dead QMh)
    {
      Segs a = {{Wvt, nullptr, nullptr, nullptr}};
      Segs bb = {{Eh, nullptr, nullptr, nullptr}};
      gemm3<2><<<dim3(8, 32), 256, 0, stream>>>(a, 1024, bb, 1024, (void*)Vt, 4096,
                                                nullptr, nullptr, 0.f, 1);
    }
    // 5) row softmax -> P bf16, in place over scores rows (row stride 8192 ushorts)
    softmax_rows<<<4096, 256, 0, stream>>>(scores);
    // 6) out = P @ V: A=P (4 segs of 1024), B=Vt (4 col-segs), fp32 store
    {
      const unsigned short* P = (const unsigned short*)scores;
      Segs a = {{P, P + 1024, P + 2048, P + 3072}};
      Segs bb = {{Vt, Vt + 1024, Vt + 2048, Vt + 3072}};
      gemm3<3><<<dim3(32, 8), 256, 0, stream>>>(a, 8192, bb, 4096, (void*)outb, 1024,
                                                nullptr, nullptr, 0.f, 4);
    }
  }
}

// Round 5
// 631.482 us; speedup vs baseline: 1.0897x; 1.0897x over previous
//
#include <hip/hip_runtime.h>

// Self-attention B=2, S=4096, D=1024, fp32 in/out.
//
// Round-5: QM trick + round-2-proven SPLIT engine.
//   * scores = (E*M)*E^T with M = Wq*Wk^T precomputed once from the
//     ORIGINAL row-major weights (round-4-verified orientation):
//     Mt[d'][d] = sum_e Wk[d'][e]*Wq[d][e]  (NT-GEMM A=Wk, B=Wq).
//   * All fp32-emulated GEMMs use the round-2 SPLIT kernel: hi/lo tiles
//     co-staged in LDS, 3 MFMAs (hh, hl, lh) per fragment pair -- 12 MFMA
//     per staged tile vs tripled-K's 8 (round-4 regression reverted).
//   * Engine: m97-style 128x128x32, global_load_lds width-16.
//
// Per batch: split_emb -> QMproj(SPLIT) -> scores(SPLIT,+mask,scale,fp32)
// -> Vtproj(plain) -> in-place softmax (bf16 P over fp32 rows) -> PV(plain).

#define S_LEN 4096

typedef __bf16 bf16x8 __attribute__((ext_vector_type(8)));
typedef float f32x4 __attribute__((ext_vector_type(4)));

__device__ __forceinline__ unsigned short f2bf(float x) {
  unsigned u = __float_as_uint(x);
  unsigned r = u + 0x7fffu + ((u >> 16) & 1u);  // round-to-nearest-even
  return (unsigned short)(r >> 16);
}
__device__ __forceinline__ float bf2f(unsigned short h) {
  return __uint_as_float(((unsigned)h) << 16);
}

__device__ __forceinline__ void gl_lds16(const void* g, void* l) {
  __builtin_amdgcn_global_load_lds(
      (const __attribute__((address_space(1))) void*)g,
      (__attribute__((address_space(3))) void*)l, 16, 0, 0);
}

// ---------------------------------------------------------------------------
// split32: fp32 -> (hi, lo) bf16 pair, elementwise, float4-vectorized.
// grid * 256 * 4 must equal the element count.
__launch_bounds__(256)
__global__ void split32(const float* __restrict__ e,
                        unsigned short* __restrict__ Eh,
                        unsigned short* __restrict__ El) {
  int i = blockIdx.x * 256 + threadIdx.x;  // float4 index
  float4 v = reinterpret_cast<const float4*>(e)[i];
  ushort4 h, l;
  h.x = f2bf(v.x); l.x = f2bf(v.x - bf2f(h.x));
  h.y = f2bf(v.y); l.y = f2bf(v.y - bf2f(h.y));
  h.z = f2bf(v.z); l.z = f2bf(v.z - bf2f(h.z));
  h.w = f2bf(v.w); l.w = f2bf(v.w - bf2f(h.w));
  reinterpret_cast<ushort4*>(Eh)[i] = h;
  reinterpret_cast<ushort4*>(El)[i] = l;
}

// ---------------------------------------------------------------------------
// prep_wv: Wv[d][e] -> Wvt[e][d] plain bf16. 32x32 LDS transpose.
__launch_bounds__(256)
__global__ void prep_wv(const float* __restrict__ wv, unsigned short* __restrict__ Wvt) {
  __shared__ float tile[32][33];
  const int bx = blockIdx.x * 32;  // e block
  const int by = blockIdx.y * 32;  // d block
  const int tx = threadIdx.x;      // 0..31
  const int ty = threadIdx.y;      // 0..7
#pragma unroll
  for (int j = 0; j < 4; ++j)
    tile[ty + j * 8][tx] = wv[(long)(by + ty + j * 8) * 1024 + bx + tx];
  __syncthreads();
#pragma unroll
  for (int j = 0; j < 4; ++j) {
    float v = tile[tx][ty + j * 8];  // = Wv[by+tx][bx+ty+j*8]
    Wvt[(long)(bx + ty + j * 8) * 1024 + by + tx] = f2bf(v);
  }
}

// ---------------------------------------------------------------------------
// NT GEMM: C[m][n] = sum_k A[m][k]*B[n][k].  BM=BN=128, BK=32, 4 waves,
// 4x4 16x16x32 fragments per wave.  SPLIT=1: A,B are (hi,lo) pairs staged
// together, 3 MFMA products {hh,hl,lh} per fragment pair (fp32 emulation).
// MODE 0: hi/lo bf16 pair store (Cp=hi, C2=lo)    [Mt precompute, QM proj]
// MODE 1: fp32 store of acc*scale + mask_filled^T  [scores]
// MODE 2: plain bf16 store                         [Vt projection]
// MODE 3: fp32 store                               [output PV]
template <int SPLIT, int MODE>
__launch_bounds__(256)
__global__ void gemm_bt(const unsigned short* __restrict__ Ah,
                        const unsigned short* __restrict__ Al, int lda,
                        const unsigned short* __restrict__ Bh,
                        const unsigned short* __restrict__ Bl, int ldb,
                        void* __restrict__ Cp, int ldc,
                        unsigned short* __restrict__ C2,
                        const float* __restrict__ mask, float scale, int kIters) {
  __shared__ unsigned short lAh[128 * 32];
  __shared__ unsigned short lBh[128 * 32];
  __shared__ unsigned short lAl[SPLIT ? 128 * 32 : 8];
  __shared__ unsigned short lBl[SPLIT ? 128 * 32 : 8];

  const int t = threadIdx.x;
  const int w = t >> 6;
  const int lane = t & 63;
  const int g = lane >> 4;
  const int r = lane & 15;
  const int wm = (w >> 1) * 64;
  const int wn = (w & 1) * 64;
  const long bm = (long)blockIdx.x * 128;
  const long bn = (long)blockIdx.y * 128;

  f32x4 acc[4][4];
  const f32x4 vzero = {0.f, 0.f, 0.f, 0.f};
#pragma unroll
  for (int mi = 0; mi < 4; ++mi)
#pragma unroll
    for (int ni = 0; ni < 4; ++ni) acc[mi][ni] = vzero;

  for (int kt = 0; kt < kIters; ++kt) {
    __syncthreads();
    const long kbase = (long)kt * 32;
#pragma unroll
    for (int i = 0; i < 2; ++i) {
      // chunk c in [0,512): 16B granules of the 128x32 bf16 tile (row-major)
      int c = (i * 4 + w) * 64 + lane;
      int row = c >> 2;
      int ko = (c & 3) * 8;
      long goffA = (bm + row) * (long)lda + kbase + ko;
      long goffB = (bn + row) * (long)ldb + kbase + ko;
      int lbase = (i * 4 + w) * 512;  // wave-uniform LDS base (ushort units)
      gl_lds16(Ah + goffA, lAh + lbase);
      gl_lds16(Bh + goffB, lBh + lbase);
      if constexpr (SPLIT) {
        gl_lds16(Al + goffA, lAl + lbase);
        gl_lds16(Bl + goffB, lBl + lbase);
      }
    }
    __syncthreads();

    bf16x8 af[4], bfh[4], af2[4], bf2v[4];
#pragma unroll
    for (int mi = 0; mi < 4; ++mi) {
      int rowa = wm + mi * 16 + r;
      af[mi] = *reinterpret_cast<const bf16x8*>(&lAh[rowa * 32 + g * 8]);
      if constexpr (SPLIT)
        af2[mi] = *reinterpret_cast<const bf16x8*>(&lAl[rowa * 32 + g * 8]);
    }
#pragma unroll
    for (int ni = 0; ni < 4; ++ni) {
      int rowb = wn + ni * 16 + r;
      bfh[ni] = *reinterpret_cast<const bf16x8*>(&lBh[rowb * 32 + g * 8]);
      if constexpr (SPLIT)
        bf2v[ni] = *reinterpret_cast<const bf16x8*>(&lBl[rowb * 32 + g * 8]);
    }
#pragma unroll
    for (int mi = 0; mi < 4; ++mi)
#pragma unroll
      for (int ni = 0; ni < 4; ++ni) {
        acc[mi][ni] = __builtin_amdgcn_mfma_f32_16x16x32_bf16(af[mi], bfh[ni], acc[mi][ni], 0, 0, 0);
        if constexpr (SPLIT) {
          acc[mi][ni] = __builtin_amdgcn_mfma_f32_16x16x32_bf16(af[mi], bf2v[ni], acc[mi][ni], 0, 0, 0);
          acc[mi][ni] = __builtin_amdgcn_mfma_f32_16x16x32_bf16(af2[mi], bfh[ni], acc[mi][ni], 0, 0, 0);
        }
      }
  }

  // Epilogue. C/D layout: col = lane&15, row = 4*(lane>>4) + reg (m89-verified).
#pragma unroll
  for (int mi = 0; mi < 4; ++mi) {
#pragma unroll
    for (int ni = 0; ni < 4; ++ni) {
      long row0 = bm + wm + mi * 16 + g * 4;
      long col = bn + wn + ni * 16 + r;
#pragma unroll
      for (int q = 0; q < 4; ++q) {
        float v = acc[mi][ni][q];
        long row = row0 + q;
        if constexpr (MODE == 0) {
          unsigned short h = f2bf(v);
          ((unsigned short*)Cp)[row * (long)ldc + col] = h;
          C2[row * (long)ldc + col] = f2bf(v - bf2f(h));
        } else if constexpr (MODE == 1) {
          // scores[q_row][k_col]: add mask_filled.T = mask[k][q] (or -inf)
          float mv = mask[col * (long)S_LEN + row];
          v = v * scale;
          v = (mv == 0.0f) ? -__builtin_inff() : (v + mv);
          ((float*)Cp)[row * (long)ldc + col] = v;
        } else if constexpr (MODE == 2) {
          ((unsigned short*)Cp)[row * (long)ldc + col] = f2bf(v);
        } else {
          ((float*)Cp)[row * (long)ldc + col] = v;
        }
      }
    }
  }
}

// ---------------------------------------------------------------------------
// Row softmax, IN PLACE: reads 4096 fp32 of row blockIdx.x, writes 4096 bf16
// into the first half of the same row's storage (row stride stays 8192 ushorts).
__launch_bounds__(256)
__global__ void softmax_rows(float* __restrict__ Sc) {
  const long row = blockIdx.x;
  float* sr = Sc + row * (long)S_LEN;
  unsigned short* pr = (unsigned short*)sr;
  const int t = threadIdx.x;
  const int lane = t & 63, wid = t >> 6;

  float4 x[4];
  float m = -3.0e38f;
#pragma unroll
  for (int i = 0; i < 4; ++i) {
    x[i] = reinterpret_cast<const float4*>(sr)[t + i * 256];
    m = fmaxf(m, fmaxf(fmaxf(x[i].x, x[i].y), fmaxf(x[i].z, x[i].w)));
  }
#pragma unroll
  for (int o = 32; o; o >>= 1) m = fmaxf(m, __shfl_xor(m, o));
  __shared__ float redm[4];
  __shared__ float reds[4];
  if (lane == 0) redm[wid] = m;
  __syncthreads();
  m = fmaxf(fmaxf(redm[0], redm[1]), fmaxf(redm[2], redm[3]));

  float e[16];
  float s = 0.f;
#pragma unroll
  for (int i = 0; i < 4; ++i) {
    e[i * 4 + 0] = __expf(x[i].x - m);
    e[i * 4 + 1] = __expf(x[i].y - m);
    e[i * 4 + 2] = __expf(x[i].z - m);
    e[i * 4 + 3] = __expf(x[i].w - m);
    s += e[i * 4 + 0] + e[i * 4 + 1] + e[i * 4 + 2] + e[i * 4 + 3];
  }
#pragma unroll
  for (int o = 32; o; o >>= 1) s += __shfl_xor(s, o);
  if (lane == 0) reds[wid] = s;
  __syncthreads();
  s = reds[0] + reds[1] + reds[2] + reds[3];
  float inv = 1.0f / s;
#pragma unroll
  for (int i = 0; i < 4; ++i) {
    ushort4 o4;
    o4.x = f2bf(e[i * 4 + 0] * inv);
    o4.y = f2bf(e[i * 4 + 1] * inv);
    o4.z = f2bf(e[i * 4 + 2] * inv);
    o4.w = f2bf(e[i * 4 + 3] * inv);
    reinterpret_cast<ushort4*>(pr)[t + i * 256] = o4;
  }
}

// ---------------------------------------------------------------------------
extern "C" void kernel_launch(void* const* d_in, const int* in_sizes, int n_in,
                              void* d_out, int out_size, void* d_ws, size_t ws_size,
                              hipStream_t stream) {
  const float* emb  = (const float*)d_in[0];
  const float* mask = (const float*)d_in[1];
  const float* wq   = (const float*)d_in[2];
  const float* wk   = (const float*)d_in[3];
  const float* wv   = (const float*)d_in[4];
  float* out = (float*)d_out;
  char* ws = (char*)d_ws;

  // Workspace layout (bytes):
  //  0        Eh   [4096][1024] bf16   8,388,608
  //  8388608  El   [4096][1024] bf16   8,388,608
  //  16777216 QMh  [4096][1024] bf16   8,388,608  (after scores: Vt [1024][4096] aliases)
  //  25165824 QMl  [4096][1024] bf16   8,388,608
  //  33554432 MtH  [1024][1024] bf16   2,097,152  (Mt[d'][d] = sum_e Wk[d'][e] Wq[d][e])
  //  35651584 MtL  [1024][1024] bf16   2,097,152
  //  37748736 Wvt  [1024][1024] bf16   2,097,152
  //  39845888 scores [4096][4096] f32 67,108,864
  //    (start of scores region aliases: WqH 2M | WqL 2M | WkH 2M | WkL 2M,
  //     dead before the first scores write)
  //  need = 106,954,752  (round-2-proven envelope: 109,051,904)
  const size_t need = 106954752;
  if (ws_size < need) return;  // clean absmax fail instead of a fault (diagnostic)

  unsigned short* Eh  = (unsigned short*)(ws);
  unsigned short* El  = (unsigned short*)(ws + 8388608);
  unsigned short* QMh = (unsigned short*)(ws + 16777216);
  unsigned short* QMl = (unsigned short*)(ws + 25165824);
  unsigned short* Vt  = QMh;  // alias, live only after scores
  unsigned short* MtH = (unsigned short*)(ws + 33554432);
  unsigned short* MtL = (unsigned short*)(ws + 35651584);
  unsigned short* Wvt = (unsigned short*)(ws + 37748736);
  float* scores       = (float*)(ws + 39845888);
  unsigned short* WqH = (unsigned short*)(ws + 39845888);
  unsigned short* WqL = (unsigned short*)(ws + 39845888 + 2097152);
  unsigned short* WkH = (unsigned short*)(ws + 39845888 + 4194304);
  unsigned short* WkL = (unsigned short*)(ws + 39845888 + 6291456);

  // ---- once: split weights (ORIGINAL layout), transpose Wv, precompute Mt --
  split32<<<1024, 256, 0, stream>>>(wq, WqH, WqL);
  split32<<<1024, 256, 0, stream>>>(wk, WkH, WkL);
  prep_wv<<<dim3(32, 32), dim3(32, 8), 0, stream>>>(wv, Wvt);
  // Mt[d'][d] = sum_e Wk[d'][e]*Wq[d][e]: SPLIT NT-GEMM, A=Wk, B=Wq.
  gemm_bt<1, 0><<<dim3(8, 8), 256, 0, stream>>>(
      WkH, WkL, 1024, WqH, WqL, 1024, (void*)MtH, 1024, MtL, nullptr, 0.f, 32);

  for (int b = 0; b < 2; ++b) {
    const float* embb = emb + (size_t)b * 4096 * 1024;
    float* outb = out + (size_t)b * 4096 * 1024;

    // 1) split embeddings into bf16 hi/lo
    split32<<<4096, 256, 0, stream>>>(embb, Eh, El);
    // 2) QM[s][d'] = sum_d E[s][d]*Mt[d'][d]: SPLIT, A=E, B=Mt, hi/lo store
    gemm_bt<1, 0><<<dim3(32, 8), 256, 0, stream>>>(
        Eh, El, 1024, MtH, MtL, 1024, (void*)QMh, 1024, QMl, nullptr, 0.f, 32);
    // 3) scores = (QM * E^T)/32 + mask_filled^T: SPLIT, A=QM, B=E, fp32 store
    gemm_bt<1, 1><<<dim3(32, 32), 256, 0, stream>>>(
        QMh, QMl, 1024, Eh, El, 1024, (void*)scores, 4096, nullptr, mask, 0.03125f, 32);
    // 4) Vt[e][s] = sum_d Wvt[e][d]*E[s][d] (plain bf16; overwrites dead QMh)
    gemm_bt<0, 2><<<dim3(8, 32), 256, 0, stream>>>(
        Wvt, nullptr, 1024, Eh, nullptr, 1024, (void*)Vt, 4096, nullptr, nullptr, 0.f, 32);
    // 5) row softmax -> P bf16, in place over scores rows (row stride 8192 ushorts)
    softmax_rows<<<4096, 256, 0, stream>>>(scores);
    // 6) out = P @ V: plain, A=P (lda 8192 ushorts), B=Vt, fp32 store
    gemm_bt<0, 3><<<dim3(32, 8), 256, 0, stream>>>(
        (unsigned short*)scores, nullptr, 8192, Vt, nullptr, 4096,
        (void*)outb, 1024, nullptr, nullptr, 0.f, 128);
  }
}